// Round 2
// baseline (695.867 us; speedup 1.0000x reference)
//
#include <hip/hip_runtime.h>

#define H    128
#define T    512
#define DX   4
#define BB   220
#define SAMP 10
#define NS   (BB*SAMP)
#define M    16       // sequences per block
#define HSTR 168      // hbuf row stride in halves (336 B, 16B-aligned)
#define NBLK 14       // ceil(220/16)

typedef _Float16 half8 __attribute__((ext_vector_type(8)));
typedef float    f32x4 __attribute__((ext_vector_type(4)));

// workspace layout (fp32 elements)
#define WS_TEMB 0
#define WS_AEMB (WS_TEMB + BB*H)
#define WS_FEMB (WS_AEMB + BB*H)
#define WS_TA   (WS_FEMB + BB*H)
#define WS_TF   (WS_TA + NS*H)
#define WS_AN   (WS_TF + NS*H)
#define WS_FA   (WS_AN + NS*H)
#define WS_FLAGS (WS_FA + NS*H)   // 2 ints: [0]=float-inputs-are-bf16, [1]=ints-are-int64

__device__ static inline float bf2f(unsigned short u) {
  unsigned int i = ((unsigned int)u) << 16;
  return __builtin_bit_cast(float, i);
}
__device__ static inline unsigned short f2bf(float f) {
  unsigned int i = __builtin_bit_cast(unsigned int, f);
  i += 0x7fffu + ((i >> 16) & 1u);
  return (unsigned short)(i >> 16);
}
__device__ static inline float loadF(const void* p, size_t i, int isbf) {
  return isbf ? bf2f(((const unsigned short*)p)[i]) : ((const float*)p)[i];
}
__device__ static inline int loadI(const void* p, int i, int is64) {
  return is64 ? (int)((const unsigned int*)p)[2*(size_t)i] : ((const int*)p)[i];
}
__device__ static inline float frcp(float x) { return __builtin_amdgcn_rcpf(x); }
__device__ static inline float sigm(float x) { return frcp(1.f + __expf(-x)); }
__device__ static inline float tanhx(float x) { return 1.f - 2.f*frcp(1.f + __expf(2.f*x)); }
__device__ static inline float scrub(float x) { return (x == x) ? x : 0.f; }
__device__ static inline int clampT(int v) { v = v - 1; if (v < 0) v = 0; if (v > T-1) v = T-1; return v; }

// ---- dtype detector: runs first, writes flags into ws
__global__ void detect(const void* __restrict__ whh, const void* __restrict__ len0,
                       int* __restrict__ flags) {
  if (threadIdx.x == 0 && blockIdx.x == 0) {
    const unsigned int* w = (const unsigned int*)whh;
    int cnt = 0;
    for (int i = 0; i < 64; ++i) {
      unsigned int lo = w[i] & 0xFFFFu;
      int e = (int)((lo >> 7) & 0xFFu);      // bf16 exponent field of the low half
      if (e >= 100 && e <= 130) ++cnt;       // plausible for |w|~0.09 weights
    }
    flags[0] = (cnt >= 40);                  // bf16-packed if most low-halves plausible
    const unsigned int* l = (const unsigned int*)len0;
    flags[1] = ((l[1] | l[3] | l[5] | l[7]) == 0u);  // int64 if odd (high) words zero
  }
}

__global__ __launch_bounds__(512, 2) void lstm_scan(
    const void* __restrict__ x0_, const void* __restrict__ len0,
    const void* __restrict__ sub_ta, const void* __restrict__ sub_tf,
    const void* __restrict__ x1_, const void* __restrict__ len1,
    const void* __restrict__ sub_an,
    const void* __restrict__ x2_, const void* __restrict__ len2,
    const void* __restrict__ sub_fa,
    const void* __restrict__ Wih, const void* __restrict__ Whh,
    const void* __restrict__ bih, const void* __restrict__ bhh,
    float* __restrict__ ws)
{
  const int e      = blockIdx.y;
  const int s0     = blockIdx.x * M;
  const int nvalid = (BB - s0) < M ? (BB - s0) : M;
  const int tid    = threadIdx.x;
  const int lane   = tid & 63;
  const int w      = tid >> 6;     // wave 0..7, owns h-cols [16w,16w+16)
  const int lo     = lane & 15;
  const int quad   = lane >> 4;

  const int* fl = (const int*)(ws + WS_FLAGS);
  const int fbf = fl[0], f64 = fl[1];

  const void* xin  = (e==0) ? x0_ : (e==1 ? x1_ : x2_);
  const void* lenp = (e==0) ? len0 : (e==1 ? len1 : len2);

  __shared__ __align__(16) _Float16 hbuf[2][M][HSTR];  // h'(t) double-buffered, K=160 used
  __shared__ unsigned int xb[M][T+1];                  // f16x2 packed x, stride 513

  // ---- zero both h buffers (2*M*HSTR halves = M*HSTR uints)
  {
    unsigned int* hz = (unsigned int*)hbuf;
    for (int i = tid; i < M*HSTR; i += 512) hz[i] = 0u;
  }
  // ---- stage x[:, :, 0:2] to LDS as f16 pairs
  for (int i = tid; i < M*T; i += 512) {
    int m = i >> 9, t = i & (T-1);
    unsigned int v = 0u;
    if (m < nvalid) {
      size_t base = ((size_t)(s0+m)*T + t) * DX;
      _Float16 ha = (_Float16)loadF(xin, base + 0, fbf);
      _Float16 hb = (_Float16)loadF(xin, base + 1, fbf);
      v = (unsigned int)__builtin_bit_cast(unsigned short, ha)
        | ((unsigned int)__builtin_bit_cast(unsigned short, hb) << 16);
    }
    xb[m][t] = v;
  }
  // ---- weight B-fragments: W' = [W_hh | W_ih | b_ih+b_hh | 0] as K=160
  half8 Bf[4][5];
  #pragma unroll
  for (int q = 0; q < 4; ++q) {
    const int g = q*128 + w*16 + lo;
    #pragma unroll
    for (int kt = 0; kt < 5; ++kt) {
      #pragma unroll
      for (int j = 0; j < 8; ++j) {
        const int k = kt*32 + quad*8 + j;
        float v;
        if      (k < 128)  v = loadF(Whh, (size_t)g*H + k, fbf);
        else if (k == 128) v = loadF(Wih, (size_t)g*2 + 0, fbf);
        else if (k == 129) v = loadF(Wih, (size_t)g*2 + 1, fbf);
        else if (k == 130) v = loadF(bih, g, fbf) + loadF(bhh, g, fbf);
        else               v = 0.f;
        Bf[q][kt][j] = (_Float16)v;
      }
    }
  }
  // ---- per-thread output slot (time watcher)
  int    my_time = -1, my_m = 0;
  float* my_dst  = nullptr;
  if (e == 0) {
    if (tid < nvalid*21) {
      int m = tid / 21, j = tid - m*21, sg = s0 + m;
      my_m = m;
      if (j == 0)       { my_time = clampT(loadI(lenp, sg, f64));            my_dst = ws + WS_TEMB + (size_t)sg*H; }
      else if (j <= 10) { int k = sg*10 + (j-1);  my_time = clampT(loadI(sub_ta, k, f64)); my_dst = ws + WS_TA + (size_t)k*H; }
      else              { int k = sg*10 + (j-11); my_time = clampT(loadI(sub_tf, k, f64)); my_dst = ws + WS_TF + (size_t)k*H; }
    }
  } else {
    if (tid < nvalid*11) {
      int m = tid / 11, j = tid - m*11, sg = s0 + m;
      my_m = m;
      if (j == 0) { my_time = clampT(loadI(lenp, sg, f64)); my_dst = ws + (e==1 ? WS_AEMB : WS_FEMB) + (size_t)sg*H; }
      else {
        int k = sg*10 + (j-1);
        if (e == 1) { my_time = clampT(loadI(sub_an, k, f64)); my_dst = ws + WS_AN + (size_t)k*H; }
        else        { my_time = clampT(loadI(sub_fa, k, f64)); my_dst = ws + WS_FA + (size_t)k*H; }
      }
    }
  }
  __syncthreads();
  // ---- constant-1 column + x(0) into buffer 0
  if (tid < M && tid < nvalid) {
    hbuf[0][tid][130] = (_Float16)1.0f;
    hbuf[1][tid][130] = (_Float16)1.0f;
    *(unsigned int*)&hbuf[0][tid][128] = xb[tid][0];
  }
  __syncthreads();

  float cr0 = 0.f, cr1 = 0.f, cr2 = 0.f, cr3 = 0.f;
  const int col = w*16 + lo;

  for (int t = 0; t < T; ++t) {
    const int p = t & 1, qn = p ^ 1;
    half8 A[5];
    #pragma unroll
    for (int kt = 0; kt < 5; ++kt)
      A[kt] = *(const half8*)&hbuf[p][lo][kt*32 + quad*8];

    f32x4 G[4];
    #pragma unroll
    for (int q = 0; q < 4; ++q) {
      f32x4 acc = {0.f, 0.f, 0.f, 0.f};
      #pragma unroll
      for (int kt = 0; kt < 5; ++kt)
        acc = __builtin_amdgcn_mfma_f32_16x16x32_f16(A[kt], Bf[q][kt], acc, 0, 0, 0);
      G[q] = acc;
    }
    float hh0, hh1, hh2, hh3;
    {
      float si, sf, tg, so, c;
      si = sigm(scrub(G[0][0])); sf = sigm(scrub(G[1][0])); tg = tanhx(scrub(G[2][0])); so = sigm(scrub(G[3][0]));
      c = sf*cr0 + si*tg; cr0 = c; hh0 = so*tanhx(c);
      si = sigm(scrub(G[0][1])); sf = sigm(scrub(G[1][1])); tg = tanhx(scrub(G[2][1])); so = sigm(scrub(G[3][1]));
      c = sf*cr1 + si*tg; cr1 = c; hh1 = so*tanhx(c);
      si = sigm(scrub(G[0][2])); sf = sigm(scrub(G[1][2])); tg = tanhx(scrub(G[2][2])); so = sigm(scrub(G[3][2]));
      c = sf*cr2 + si*tg; cr2 = c; hh2 = so*tanhx(c);
      si = sigm(scrub(G[0][3])); sf = sigm(scrub(G[1][3])); tg = tanhx(scrub(G[2][3])); so = sigm(scrub(G[3][3]));
      c = sf*cr3 + si*tg; cr3 = c; hh3 = so*tanhx(c);
    }
    hbuf[qn][quad*4 + 0][col] = (_Float16)hh0;
    hbuf[qn][quad*4 + 1][col] = (_Float16)hh1;
    hbuf[qn][quad*4 + 2][col] = (_Float16)hh2;
    hbuf[qn][quad*4 + 3][col] = (_Float16)hh3;
    if (tid < M) {
      unsigned int xv = (t+1 < T) ? xb[tid][t+1] : 0u;
      *(unsigned int*)&hbuf[qn][tid][128] = xv;   // x(t+1); zeros for invalid seqs
    }
    __syncthreads();
    if (my_time == t) {
      const _Float16* src = hbuf[qn][my_m];
      #pragma unroll
      for (int i = 0; i < H; i += 8) {
        half8 v = *(const half8*)&src[i];
        #pragma unroll
        for (int j = 0; j < 8; ++j) my_dst[i+j] = (float)v[j];
      }
    }
  }
}

__global__ void dists(const float* __restrict__ ws, void* __restrict__ outv) {
  const int fbf = ((const int*)(ws + WS_FLAGS))[0];
  const int gtid = blockIdx.x*256 + threadIdx.x;
  const int widx = gtid >> 6, lane = gtid & 63;
  const float *pa, *pb;
  if (widx < 220)       { pa = ws + WS_TEMB + (size_t)widx*H;        pb = ws + WS_AEMB + (size_t)widx*H; }
  else if (widx < 440)  { int b = widx-220;  pa = ws + WS_TEMB + (size_t)b*H; pb = ws + WS_FEMB + (size_t)b*H; }
  else if (widx < 2640) { int k = widx-440;  pa = ws + WS_TA + (size_t)k*H;   pb = ws + WS_AN + (size_t)k*H; }
  else                  { int k = widx-2640; pa = ws + WS_TF + (size_t)k*H;   pb = ws + WS_FA + (size_t)k*H; }
  float d0 = pa[lane]    - pb[lane];
  float d1 = pa[lane+64] - pb[lane+64];
  float s  = scrub(d0*d0 + d1*d1);
  #pragma unroll
  for (int off = 32; off > 0; off >>= 1) s += __shfl_down(s, off, 64);
  if (lane == 0) {
    float r = __expf(-sqrtf(s));
    if (fbf) ((unsigned short*)outv)[widx] = f2bf(r);
    else     ((float*)outv)[widx] = r;
  }
}

extern "C" void kernel_launch(void* const* d_in, const int* in_sizes, int n_in,
                              void* d_out, int out_size, void* d_ws, size_t ws_size,
                              hipStream_t stream) {
  float* ws = (float*)d_ws;
  hipLaunchKernelGGL(detect, dim3(1), dim3(64), 0, stream,
                     d_in[11], d_in[1], (int*)(ws + WS_FLAGS));
  hipLaunchKernelGGL(lstm_scan, dim3(NBLK, 3), dim3(512), 0, stream,
                     d_in[0], d_in[1], d_in[2], d_in[3],
                     d_in[4], d_in[5], d_in[6],
                     d_in[7], d_in[8], d_in[9],
                     d_in[10], d_in[11], d_in[12], d_in[13], ws);
  hipLaunchKernelGGL(dists, dim3(4840*64/256), dim3(256), 0, stream, ws, d_out);
}